// Round 7
// baseline (125.317 us; speedup 1.0000x reference)
//
#include <hip/hip_runtime.h>

#define FIN 128
#define FOUT 128
#define KNB 32
#define QD 16   // dwords per node per quarter (32 features as fp16 pairs)

typedef __attribute__((ext_vector_type(8))) short bf16x8;
typedef __attribute__((ext_vector_type(4))) float f32x4;

// ---- Kernel 0: stage W (fp32 [128][128]) -> bf16 A-fragments for 16x16x32 ----
__global__ __launch_bounds__(256) void wf_stage(
    const float* __restrict__ W, unsigned* __restrict__ wf) {
  const int id = blockIdx.x * 256 + threadIdx.x;   // 0..2047
  if (id >= 2048) return;
  const int lane = id & 63;
  const int kb = (id >> 6) & 3;
  const int ct = id >> 8;
  const int krow = kb * 32 + (lane >> 4) * 8;
  const int col = ct * 16 + (lane & 15);
  unsigned d[4];
  #pragma unroll
  for (int p = 0; p < 4; ++p) {
    const float lo = W[(krow + 2 * p) * FOUT + col];
    const float hi = W[(krow + 2 * p + 1) * FOUT + col];
    asm("v_cvt_pk_bf16_f32 %0, %1, %2" : "=v"(d[p]) : "v"(lo), "v"(hi));
  }
  uint4 q; q.x = d[0]; q.y = d[1]; q.z = d[2]; q.w = d[3];
  *(uint4*)(wf + (size_t)id * 4) = q;
}

// ---- Kernel 1: h_q[4][n][16] (fp16 pairs) = x @ W via bf16 MFMA ----
// wf staged in LDS; wave owns 16 x-rows x 128 cols -> x read exactly once.
__global__ __launch_bounds__(256) void gemm_mfma(
    const float* __restrict__ x, const unsigned* __restrict__ wf,
    unsigned* __restrict__ h, int n_rows) {
  __shared__ uint4 wls[2048];    // 32 KB: all W fragments
  const int t = threadIdx.x;
  #pragma unroll
  for (int i = 0; i < 8; ++i)
    wls[i * 256 + t] = ((const uint4*)wf)[i * 256 + t];
  __syncthreads();

  const int l = t & 63;
  const int kq = l >> 4;   // 0..3
  const int row = blockIdx.x * 64 + (t >> 6) * 16 + (l & 15);
  const int rsafe = min(row, n_rows - 1);

  bf16x8 xf[4];
  #pragma unroll
  for (int kb = 0; kb < 4; ++kb) {
    const float* xp = x + (size_t)rsafe * FIN + kb * 32 + kq * 8;
    const float4 x0 = *(const float4*)(xp);
    const float4 x1 = *(const float4*)(xp + 4);
    union { unsigned u[4]; bf16x8 v; } pk;
    asm("v_cvt_pk_bf16_f32 %0, %1, %2" : "=v"(pk.u[0]) : "v"(x0.x), "v"(x0.y));
    asm("v_cvt_pk_bf16_f32 %0, %1, %2" : "=v"(pk.u[1]) : "v"(x0.z), "v"(x0.w));
    asm("v_cvt_pk_bf16_f32 %0, %1, %2" : "=v"(pk.u[2]) : "v"(x1.x), "v"(x1.y));
    asm("v_cvt_pk_bf16_f32 %0, %1, %2" : "=v"(pk.u[3]) : "v"(x1.z), "v"(x1.w));
    xf[kb] = pk.v;
  }

  #pragma unroll
  for (int ct = 0; ct < 8; ++ct) {
    f32x4 acc = {0.f, 0.f, 0.f, 0.f};
    #pragma unroll
    for (int kb = 0; kb < 4; ++kb) {
      union { uint4 q; bf16x8 v; } af;
      af.q = wls[(ct * 4 + kb) * 64 + l];
      acc = __builtin_amdgcn_mfma_f32_16x16x32_bf16(af.v, xf[kb], acc, 0, 0, 0);
    }
    if (row < n_rows) {
      unsigned p0, p1;
      asm("v_cvt_pkrtz_f16_f32 %0, %1, %2" : "=v"(p0) : "v"(acc[0]), "v"(acc[1]));
      asm("v_cvt_pkrtz_f16_f32 %0, %1, %2" : "=v"(p1) : "v"(acc[2]), "v"(acc[3]));
      uint2 st; st.x = p0; st.y = p1;
      *(uint2*)(h + ((size_t)(ct >> 1) * n_rows + row) * QD + (ct & 1) * 8 + kq * 2) = st;
    }
  }
}

// ---- Kernel 2: gather + rank-15-of-32 median (R5 structure + nt hints) ----
__device__ __forceinline__ unsigned pmin(unsigned a, unsigned b) {
  unsigned r; asm("v_pk_min_f16 %0, %1, %2" : "=v"(r) : "v"(a), "v"(b)); return r;
}
__device__ __forceinline__ unsigned pmax(unsigned a, unsigned b) {
  unsigned r; asm("v_pk_max_f16 %0, %1, %2" : "=v"(r) : "v"(a), "v"(b)); return r;
}
__device__ __forceinline__ void ce(unsigned& a, unsigned& b) {
  const unsigned mn = pmin(a, b), mx = pmax(a, b);
  a = mn; b = mx;
}

// Batcher odd-even mergesort of v[base..base+15] (63 CEs)
#define OEMS16(v, base)                                                        \
  _Pragma("unroll") for (int p = 1; p < 16; p <<= 1)                           \
  _Pragma("unroll") for (int k = p; k >= 1; k >>= 1)                           \
  _Pragma("unroll") for (int j = k & (p - 1); j + k < 16; j += 2 * k)          \
  _Pragma("unroll") for (int i = 0; i < k; ++i)                                \
    if (((i + j) / (2 * p)) == ((i + j + k) / (2 * p)))                        \
      ce(v[(base) + i + j], v[(base) + i + j + k]);

// Block 256 = 16 node-quarters (16 lanes x 1 dword each). Phase q: all
// concurrent blocks read the same 3.2 MB h-quarter (L2-resident).
// nt on gathers (no L1 alloc), nt on nbrs loads and out stores (no L2 pollution).
__global__ __launch_bounds__(256) void median_gather(
    const unsigned* __restrict__ h, const int* __restrict__ nbrs,
    float* __restrict__ out, int n_nodes, int blocks_per_q) {
  __shared__ int sidx[16 * 33];   // +1-pad rows
  const int t = threadIdx.x;
  const int q  = blockIdx.x / blocks_per_q;
  const int bq = blockIdx.x - q * blocks_per_q;
  const int node_base = bq * 16;

  // stage 16 nodes x 32 idx (two nt dword loads), write to padded rows
  {
    const int e = t * 2;
    const int i0 = __builtin_nontemporal_load(nbrs + (size_t)node_base * KNB + e);
    const int i1 = __builtin_nontemporal_load(nbrs + (size_t)node_base * KNB + e + 1);
    const int nl0 = e >> 5, k0 = e & 31;
    sidx[nl0 * 33 + k0] = i0;
    sidx[nl0 * 33 + k0 + 1] = i1;
  }
  __syncthreads();

  const int nl = t >> 4;          // node within block
  const int d  = t & 15;          // dword (feature pair) within quarter
  const unsigned qbase = (unsigned)q * (unsigned)n_nodes * QD + (unsigned)d;

  int idxv[KNB];
  #pragma unroll
  for (int k = 0; k < KNB; ++k) idxv[k] = sidx[nl * 33 + k];

  unsigned v[KNB];
  #pragma unroll
  for (int k = 0; k < KNB; ++k)
    v[k] = __builtin_nontemporal_load(h + qbase + (unsigned)idxv[k] * QD);

  OEMS16(v, 0)
  OEMS16(v, 16)

  // rank-15 of union of two sorted 16-seqs: max_i min(a[i], b[15-i])
  unsigned m[16];
  #pragma unroll
  for (int i = 0; i < 16; ++i) m[i] = pmin(v[i], v[31 - i]);
  #pragma unroll
  for (int s = 8; s >= 1; s >>= 1)
    #pragma unroll
    for (int i = 0; i < s; ++i) m[i] = pmax(m[i], m[i + s]);

  // unpack two fp16 medians -> fp32 pair, nt dwordx2 store
  float flo, fhi;
  asm("v_cvt_f32_f16 %0, %1" : "=v"(flo) : "v"(m[0]));
  asm("v_cvt_f32_f16 %0, %1" : "=v"(fhi) : "v"(m[0] >> 16));
  double pack;
  {
    float2 o; o.x = flo; o.y = fhi;
    __builtin_memcpy(&pack, &o, 8);
  }
  const int node = node_base + nl;
  __builtin_nontemporal_store(
      pack, (double*)(out + (size_t)node * FOUT + q * 32 + d * 2));
}

extern "C" void kernel_launch(void* const* d_in, const int* in_sizes, int n_in,
                              void* d_out, int out_size, void* d_ws, size_t ws_size,
                              hipStream_t stream) {
  const float* x    = (const float*)d_in[0];   // [N, FIN] fp32
  const int*   nbrs = (const int*)d_in[1];     // [N, K] int32
  const float* W    = (const float*)d_in[2];   // [FIN, FOUT] fp32
  float* out = (float*)d_out;                  // [N, FOUT] fp32

  unsigned* h  = (unsigned*)d_ws;              // [4][N][16] dwords = 12.8 MB
  unsigned* wf = (unsigned*)d_ws + 3200000;    // 32 KB W fragments

  const int n = in_sizes[0] / FIN;             // 50000

  wf_stage<<<8, 256, 0, stream>>>(W, wf);
  gemm_mfma<<<(n + 63) / 64, 256, 0, stream>>>(x, wf, h, n);
  const int bpq = n / 16;                      // 3125 blocks per quarter-phase
  median_gather<<<4 * bpq, 256, 0, stream>>>(h, nbrs, out, n, bpq);
}

// Round 8
// 118.679 us; speedup vs baseline: 1.0559x; 1.0559x over previous
//
#include <hip/hip_runtime.h>

#define FIN 128
#define FOUT 128
#define KNB 32
#define QD 16   // dwords per node per quarter (32 features as fp16 pairs)

typedef __attribute__((ext_vector_type(8))) short bf16x8;
typedef __attribute__((ext_vector_type(4))) float f32x4;

// ---- Kernel 0: stage W (fp32 [128][128]) -> bf16 A-fragments for 16x16x32 ----
__global__ __launch_bounds__(256) void wf_stage(
    const float* __restrict__ W, unsigned* __restrict__ wf) {
  const int id = blockIdx.x * 256 + threadIdx.x;   // 0..2047
  if (id >= 2048) return;
  const int lane = id & 63;
  const int kb = (id >> 6) & 3;
  const int ct = id >> 8;
  const int krow = kb * 32 + (lane >> 4) * 8;
  const int col = ct * 16 + (lane & 15);
  unsigned d[4];
  #pragma unroll
  for (int p = 0; p < 4; ++p) {
    const float lo = W[(krow + 2 * p) * FOUT + col];
    const float hi = W[(krow + 2 * p + 1) * FOUT + col];
    asm("v_cvt_pk_bf16_f32 %0, %1, %2" : "=v"(d[p]) : "v"(lo), "v"(hi));
  }
  uint4 q; q.x = d[0]; q.y = d[1]; q.z = d[2]; q.w = d[3];
  *(uint4*)(wf + (size_t)id * 4) = q;
}

// ---- Kernel 1: h_q[4][n][16] (fp16 pairs) = x @ W via bf16 MFMA ----
// wf staged in LDS; wave owns 16 x-rows x 128 cols -> x read exactly once.
__global__ __launch_bounds__(256) void gemm_mfma(
    const float* __restrict__ x, const unsigned* __restrict__ wf,
    unsigned* __restrict__ h, int n_rows) {
  __shared__ uint4 wls[2048];    // 32 KB: all W fragments
  const int t = threadIdx.x;
  #pragma unroll
  for (int i = 0; i < 8; ++i)
    wls[i * 256 + t] = ((const uint4*)wf)[i * 256 + t];
  __syncthreads();

  const int l = t & 63;
  const int kq = l >> 4;   // 0..3
  const int row = blockIdx.x * 64 + (t >> 6) * 16 + (l & 15);
  const int rsafe = min(row, n_rows - 1);

  bf16x8 xf[4];
  #pragma unroll
  for (int kb = 0; kb < 4; ++kb) {
    const float* xp = x + (size_t)rsafe * FIN + kb * 32 + kq * 8;
    const float4 x0 = *(const float4*)(xp);
    const float4 x1 = *(const float4*)(xp + 4);
    union { unsigned u[4]; bf16x8 v; } pk;
    asm("v_cvt_pk_bf16_f32 %0, %1, %2" : "=v"(pk.u[0]) : "v"(x0.x), "v"(x0.y));
    asm("v_cvt_pk_bf16_f32 %0, %1, %2" : "=v"(pk.u[1]) : "v"(x0.z), "v"(x0.w));
    asm("v_cvt_pk_bf16_f32 %0, %1, %2" : "=v"(pk.u[2]) : "v"(x1.x), "v"(x1.y));
    asm("v_cvt_pk_bf16_f32 %0, %1, %2" : "=v"(pk.u[3]) : "v"(x1.z), "v"(x1.w));
    xf[kb] = pk.v;
  }

  #pragma unroll
  for (int ct = 0; ct < 8; ++ct) {
    f32x4 acc = {0.f, 0.f, 0.f, 0.f};
    #pragma unroll
    for (int kb = 0; kb < 4; ++kb) {
      union { uint4 q; bf16x8 v; } af;
      af.q = wls[(ct * 4 + kb) * 64 + l];
      acc = __builtin_amdgcn_mfma_f32_16x16x32_bf16(af.v, xf[kb], acc, 0, 0, 0);
    }
    if (row < n_rows) {
      unsigned p0, p1;
      asm("v_cvt_pkrtz_f16_f32 %0, %1, %2" : "=v"(p0) : "v"(acc[0]), "v"(acc[1]));
      asm("v_cvt_pkrtz_f16_f32 %0, %1, %2" : "=v"(p1) : "v"(acc[2]), "v"(acc[3]));
      uint2 st; st.x = p0; st.y = p1;
      *(uint2*)(h + ((size_t)(ct >> 1) * n_rows + row) * QD + (ct & 1) * 8 + kq * 2) = st;
    }
  }
}

// ---- Kernel 2: gather + rank-15-of-32 median (R5 structure, safe-NT only) ----
__device__ __forceinline__ unsigned pmin(unsigned a, unsigned b) {
  unsigned r; asm("v_pk_min_f16 %0, %1, %2" : "=v"(r) : "v"(a), "v"(b)); return r;
}
__device__ __forceinline__ unsigned pmax(unsigned a, unsigned b) {
  unsigned r; asm("v_pk_max_f16 %0, %1, %2" : "=v"(r) : "v"(a), "v"(b)); return r;
}
__device__ __forceinline__ void ce(unsigned& a, unsigned& b) {
  const unsigned mn = pmin(a, b), mx = pmax(a, b);
  a = mn; b = mx;
}

// Batcher odd-even mergesort of v[base..base+15] (63 CEs)
#define OEMS16(v, base)                                                        \
  _Pragma("unroll") for (int p = 1; p < 16; p <<= 1)                           \
  _Pragma("unroll") for (int k = p; k >= 1; k >>= 1)                           \
  _Pragma("unroll") for (int j = k & (p - 1); j + k < 16; j += 2 * k)          \
  _Pragma("unroll") for (int i = 0; i < k; ++i)                                \
    if (((i + j) / (2 * p)) == ((i + j + k) / (2 * p)))                        \
      ce(v[(base) + i + j], v[(base) + i + j + k]);

// Block 256 = 16 node-quarters (16 lanes x 1 dword each). One quarter q per
// LAUNCH (phase-pure): all concurrent blocks share the same 3.2 MB h-quarter.
// NT on nbrs (read-once) and out (write-once); h loads NORMAL (L2-resident).
__global__ __launch_bounds__(256) void median_gather(
    const unsigned* __restrict__ h, const int* __restrict__ nbrs,
    float* __restrict__ out, int n_nodes, int q) {
  __shared__ int sidx[16 * 33];   // +1-pad rows
  const int t = threadIdx.x;
  const int node_base = blockIdx.x * 16;

  // stage 16 nodes x 32 idx (read-once -> NT), write to padded rows
  {
    const int e = t * 2;
    const int i0 = __builtin_nontemporal_load(nbrs + (size_t)node_base * KNB + e);
    const int i1 = __builtin_nontemporal_load(nbrs + (size_t)node_base * KNB + e + 1);
    const int nl0 = e >> 5, k0 = e & 31;
    sidx[nl0 * 33 + k0] = i0;
    sidx[nl0 * 33 + k0 + 1] = i1;
  }
  __syncthreads();

  const int nl = t >> 4;          // node within block
  const int d  = t & 15;          // dword (feature pair) within quarter
  const unsigned qbase = (unsigned)q * (unsigned)n_nodes * QD + (unsigned)d;

  int idxv[KNB];
  #pragma unroll
  for (int k = 0; k < KNB; ++k) idxv[k] = sidx[nl * 33 + k];

  unsigned v[KNB];
  #pragma unroll
  for (int k = 0; k < KNB; ++k)
    v[k] = h[qbase + (unsigned)idxv[k] * QD];   // normal load: keep in L2

  OEMS16(v, 0)
  OEMS16(v, 16)

  // rank-15 of union of two sorted 16-seqs: max_i min(a[i], b[15-i])
  unsigned m[16];
  #pragma unroll
  for (int i = 0; i < 16; ++i) m[i] = pmin(v[i], v[31 - i]);
  #pragma unroll
  for (int s = 8; s >= 1; s >>= 1)
    #pragma unroll
    for (int i = 0; i < s; ++i) m[i] = pmax(m[i], m[i + s]);

  // unpack two fp16 medians -> fp32 pair, NT dwordx2 store (write-once stream)
  float flo, fhi;
  asm("v_cvt_f32_f16 %0, %1" : "=v"(flo) : "v"(m[0]));
  asm("v_cvt_f32_f16 %0, %1" : "=v"(fhi) : "v"(m[0] >> 16));
  double pack;
  {
    float2 o; o.x = flo; o.y = fhi;
    __builtin_memcpy(&pack, &o, 8);
  }
  const int node = node_base + nl;
  __builtin_nontemporal_store(
      pack, (double*)(out + (size_t)node * FOUT + q * 32 + d * 2));
}

extern "C" void kernel_launch(void* const* d_in, const int* in_sizes, int n_in,
                              void* d_out, int out_size, void* d_ws, size_t ws_size,
                              hipStream_t stream) {
  const float* x    = (const float*)d_in[0];   // [N, FIN] fp32
  const int*   nbrs = (const int*)d_in[1];     // [N, K] int32
  const float* W    = (const float*)d_in[2];   // [FIN, FOUT] fp32
  float* out = (float*)d_out;                  // [N, FOUT] fp32

  unsigned* h  = (unsigned*)d_ws;              // [4][N][16] dwords = 12.8 MB
  unsigned* wf = (unsigned*)d_ws + 3200000;    // 32 KB W fragments

  const int n = in_sizes[0] / FIN;             // 50000

  wf_stage<<<8, 256, 0, stream>>>(W, wf);
  gemm_mfma<<<(n + 63) / 64, 256, 0, stream>>>(x, wf, h, n);
  const int bpq = n / 16;                      // 3125 blocks per quarter-phase
  for (int q = 0; q < 4; ++q)
    median_gather<<<bpq, 256, 0, stream>>>(h, nbrs, out, n, q);
}

// Round 9
// 63.289 us; speedup vs baseline: 1.9801x; 1.8752x over previous
//
#include <hip/hip_runtime.h>

#define FIN 128
#define FOUT 128
#define KNB 32
#define QD 16   // dwords per node per quarter (32 features as fp16 pairs)

typedef __attribute__((ext_vector_type(8))) short bf16x8;
typedef __attribute__((ext_vector_type(4))) float f32x4;

// ---- Kernel 0: stage W (fp32 [128][128]) -> bf16 A-fragments for 16x16x32 ----
__global__ __launch_bounds__(256) void wf_stage(
    const float* __restrict__ W, unsigned* __restrict__ wf) {
  const int id = blockIdx.x * 256 + threadIdx.x;   // 0..2047
  if (id >= 2048) return;
  const int lane = id & 63;
  const int kb = (id >> 6) & 3;
  const int ct = id >> 8;
  const int krow = kb * 32 + (lane >> 4) * 8;
  const int col = ct * 16 + (lane & 15);
  unsigned d[4];
  #pragma unroll
  for (int p = 0; p < 4; ++p) {
    const float lo = W[(krow + 2 * p) * FOUT + col];
    const float hi = W[(krow + 2 * p + 1) * FOUT + col];
    asm("v_cvt_pk_bf16_f32 %0, %1, %2" : "=v"(d[p]) : "v"(lo), "v"(hi));
  }
  uint4 q; q.x = d[0]; q.y = d[1]; q.z = d[2]; q.w = d[3];
  *(uint4*)(wf + (size_t)id * 4) = q;
}

// ---- Kernel 1: h_q[4][n][16] (fp16 pairs) = x @ W via bf16 MFMA ----
// wf staged in LDS; wave owns 16 x-rows x 128 cols -> x read exactly once.
__global__ __launch_bounds__(256) void gemm_mfma(
    const float* __restrict__ x, const unsigned* __restrict__ wf,
    unsigned* __restrict__ h, int n_rows) {
  __shared__ uint4 wls[2048];    // 32 KB: all W fragments
  const int t = threadIdx.x;
  #pragma unroll
  for (int i = 0; i < 8; ++i)
    wls[i * 256 + t] = ((const uint4*)wf)[i * 256 + t];
  __syncthreads();

  const int l = t & 63;
  const int kq = l >> 4;   // 0..3
  const int row = blockIdx.x * 64 + (t >> 6) * 16 + (l & 15);
  const int rsafe = min(row, n_rows - 1);

  bf16x8 xf[4];
  #pragma unroll
  for (int kb = 0; kb < 4; ++kb) {
    const float* xp = x + (size_t)rsafe * FIN + kb * 32 + kq * 8;
    const float4 x0 = *(const float4*)(xp);
    const float4 x1 = *(const float4*)(xp + 4);
    union { unsigned u[4]; bf16x8 v; } pk;
    asm("v_cvt_pk_bf16_f32 %0, %1, %2" : "=v"(pk.u[0]) : "v"(x0.x), "v"(x0.y));
    asm("v_cvt_pk_bf16_f32 %0, %1, %2" : "=v"(pk.u[1]) : "v"(x0.z), "v"(x0.w));
    asm("v_cvt_pk_bf16_f32 %0, %1, %2" : "=v"(pk.u[2]) : "v"(x1.x), "v"(x1.y));
    asm("v_cvt_pk_bf16_f32 %0, %1, %2" : "=v"(pk.u[3]) : "v"(x1.z), "v"(x1.w));
    xf[kb] = pk.v;
  }

  #pragma unroll
  for (int ct = 0; ct < 8; ++ct) {
    f32x4 acc = {0.f, 0.f, 0.f, 0.f};
    #pragma unroll
    for (int kb = 0; kb < 4; ++kb) {
      union { uint4 q; bf16x8 v; } af;
      af.q = wls[(ct * 4 + kb) * 64 + l];
      acc = __builtin_amdgcn_mfma_f32_16x16x32_bf16(af.v, xf[kb], acc, 0, 0, 0);
    }
    if (row < n_rows) {
      unsigned p0, p1;
      asm("v_cvt_pkrtz_f16_f32 %0, %1, %2" : "=v"(p0) : "v"(acc[0]), "v"(acc[1]));
      asm("v_cvt_pkrtz_f16_f32 %0, %1, %2" : "=v"(p1) : "v"(acc[2]), "v"(acc[3]));
      uint2 st; st.x = p0; st.y = p1;
      *(uint2*)(h + ((size_t)(ct >> 1) * n_rows + row) * QD + (ct & 1) * 8 + kq * 2) = st;
    }
  }
}

// ---- Kernel 2: gather + rank-15-of-32 median (R5-proven structure) ----
__device__ __forceinline__ unsigned pmin(unsigned a, unsigned b) {
  unsigned r; asm("v_pk_min_f16 %0, %1, %2" : "=v"(r) : "v"(a), "v"(b)); return r;
}
__device__ __forceinline__ unsigned pmax(unsigned a, unsigned b) {
  unsigned r; asm("v_pk_max_f16 %0, %1, %2" : "=v"(r) : "v"(a), "v"(b)); return r;
}
__device__ __forceinline__ void ce(unsigned& a, unsigned& b) {
  const unsigned mn = pmin(a, b), mx = pmax(a, b);
  a = mn; b = mx;
}

// Batcher odd-even mergesort of v[base..base+15] (63 CEs)
#define OEMS16(v, base)                                                        \
  _Pragma("unroll") for (int p = 1; p < 16; p <<= 1)                           \
  _Pragma("unroll") for (int k = p; k >= 1; k >>= 1)                           \
  _Pragma("unroll") for (int j = k & (p - 1); j + k < 16; j += 2 * k)          \
  _Pragma("unroll") for (int i = 0; i < k; ++i)                                \
    if (((i + j) / (2 * p)) == ((i + j + k) / (2 * p)))                        \
      ce(v[(base) + i + j], v[(base) + i + j + k]);

// Block 256 = 16 node-quarters (16 lanes x 1 dword each). Phase q = blockIdx.x
// / blocks_per_q: all concurrent blocks read the same 3.2 MB h-quarter
// (per-XCD-L2-resident). Normal loads everywhere — NT on h loads destroys L2
// residency (R7: FETCH 67->219 MB, dur 50->105 us).
__global__ __launch_bounds__(256) void median_gather(
    const unsigned* __restrict__ h, const int* __restrict__ nbrs,
    float* __restrict__ out, int n_nodes, int blocks_per_q) {
  __shared__ int sidx[16 * 33];   // +1-pad rows
  const int t = threadIdx.x;
  const int q  = blockIdx.x / blocks_per_q;
  const int bq = blockIdx.x - q * blocks_per_q;
  const int node_base = bq * 16;

  // stage 16 nodes x 32 idx (coalesced int2), write to padded rows
  {
    const int2 p2 = *(const int2*)(nbrs + (size_t)node_base * KNB + t * 2);
    const int e = t * 2;
    const int nl0 = e >> 5, k0 = e & 31;
    sidx[nl0 * 33 + k0] = p2.x;
    sidx[nl0 * 33 + k0 + 1] = p2.y;
  }
  __syncthreads();

  const int nl = t >> 4;          // node within block
  const int d  = t & 15;          // dword (feature pair) within quarter
  const unsigned qbase = (unsigned)q * (unsigned)n_nodes * QD + (unsigned)d;

  int idxv[KNB];
  #pragma unroll
  for (int k = 0; k < KNB; ++k) idxv[k] = sidx[nl * 33 + k];

  unsigned v[KNB];
  #pragma unroll
  for (int k = 0; k < KNB; ++k)
    v[k] = h[qbase + (unsigned)idxv[k] * QD];

  OEMS16(v, 0)
  OEMS16(v, 16)

  // rank-15 of union of two sorted 16-seqs: max_i min(a[i], b[15-i])
  unsigned m[16];
  #pragma unroll
  for (int i = 0; i < 16; ++i) m[i] = pmin(v[i], v[31 - i]);
  #pragma unroll
  for (int s = 8; s >= 1; s >>= 1)
    #pragma unroll
    for (int i = 0; i < s; ++i) m[i] = pmax(m[i], m[i + s]);

  // unpack two fp16 medians -> fp32 pair
  float flo, fhi;
  asm("v_cvt_f32_f16 %0, %1" : "=v"(flo) : "v"(m[0]));
  asm("v_cvt_f32_f16 %0, %1" : "=v"(fhi) : "v"(m[0] >> 16));
  float2 o; o.x = flo; o.y = fhi;

  const int node = node_base + nl;
  *(float2*)(out + (size_t)node * FOUT + q * 32 + d * 2) = o;
}

extern "C" void kernel_launch(void* const* d_in, const int* in_sizes, int n_in,
                              void* d_out, int out_size, void* d_ws, size_t ws_size,
                              hipStream_t stream) {
  const float* x    = (const float*)d_in[0];   // [N, FIN] fp32
  const int*   nbrs = (const int*)d_in[1];     // [N, K] int32
  const float* W    = (const float*)d_in[2];   // [FIN, FOUT] fp32
  float* out = (float*)d_out;                  // [N, FOUT] fp32

  unsigned* h  = (unsigned*)d_ws;              // [4][N][16] dwords = 12.8 MB
  unsigned* wf = (unsigned*)d_ws + 3200000;    // 32 KB W fragments

  const int n = in_sizes[0] / FIN;             // 50000

  wf_stage<<<8, 256, 0, stream>>>(W, wf);
  gemm_mfma<<<(n + 63) / 64, 256, 0, stream>>>(x, wf, h, n);
  const int bpq = n / 16;                      // 3125 blocks per quarter-phase
  median_gather<<<4 * bpq, 256, 0, stream>>>(h, nbrs, out, n, bpq);
}